// Round 14
// baseline (387.444 us; speedup 1.0000x reference)
//
#include <hip/hip_runtime.h>
#include <hip/hip_fp16.h>
#include <cmath>

// ---- constants from the reference ----
constexpr float ACT_NORM = 1.6789717f;
constexpr float PW0      = 0.20412414523193154f;   // sqrt(1/24)  (== pw1/sqrt3)
constexpr float PW1      = 0.35355339059327373f;   // sqrt(3/24)
constexpr float PWREC    = 0.05590169943749474f;   // sqrt(1/320)
constexpr float INV_SQ3  = 0.57735026918962576f;
// second-layer 1/sqrt(64) folded into epilogue constants
constexpr float PW0s     = PW0 * 0.125f;
constexpr float PW1s     = PW1 * 0.125f;
constexpr float PWRECs   = PWREC * 0.125f;

__device__ __forceinline__ float silu_n(float x) {
  return x / (1.f + __expf(-x)) * ACT_NORM;
}

__device__ __forceinline__ unsigned ubcast_lane(unsigned v, int k) {
  return (unsigned)__builtin_amdgcn_readlane((int)v, k);
}

// fp16 helpers
typedef _Float16 h2v __attribute__((ext_vector_type(2)));
typedef _Float16 f16x8 __attribute__((ext_vector_type(8)));
typedef float    f32x4 __attribute__((ext_vector_type(4)));

__device__ __forceinline__ unsigned packh2(float a, float b) {
  h2v p; p.x = (_Float16)a; p.y = (_Float16)b;
  return __builtin_bit_cast(unsigned, p);
}
__device__ __forceinline__ unsigned short f16bits(float a) {
  return __builtin_bit_cast(unsigned short, (_Float16)a);
}
__device__ __forceinline__ float h2f(unsigned short b) {
  return (float)__builtin_bit_cast(_Float16, b);
}
__device__ __forceinline__ float dot2h(unsigned w2, unsigned h2, float acc) {
  return __builtin_amdgcn_fdot2(__builtin_bit_cast(h2v, w2),
                                __builtin_bit_cast(h2v, h2), acc, false);
}
__device__ __forceinline__ float hlo(unsigned d) {
  return (float)__builtin_bit_cast(_Float16, (unsigned short)(d & 0xffffu));
}
__device__ __forceinline__ float hhi(unsigned d) {
  return (float)__builtin_bit_cast(_Float16, (unsigned short)(d >> 16));
}
__device__ __forceinline__ float hsel(unsigned d, int hi) { return hi ? hhi(d) : hlo(d); }
__device__ __forceinline__ unsigned u4sel(const uint4& v, int i) {
  return i == 0 ? v.x : (i == 1 ? v.y : (i == 2 ? v.z : v.w));
}
__device__ __forceinline__ unsigned u2sel(const uint2& v, int i) { return i ? v.y : v.x; }

// mfma_f32_16x16x32_f16: A row = lane&15; B col = lane&15 (consistent k grouping);
// C/D: col=lane&15, row=(lane>>4)*4+reg [HW-verified; proven by rounds 12/13].
__device__ __forceinline__ f32x4 mfma16(uint4 a, uint4 b, f32x4 c) {
  return __builtin_amdgcn_mfma_f32_16x16x32_f16(
      __builtin_bit_cast(f16x8, a), __builtin_bit_cast(f16x8, b), c, 0, 0, 0);
}

// ---------------- CSR build: histogram -> block scan -> scatter ----------------
__global__ __launch_bounds__(256)
void hist_kernel(const int* __restrict__ ei, int* __restrict__ cnt, int E) {
  const int e = blockIdx.x * 256 + threadIdx.x;
  if (e < E) atomicAdd(&cnt[ei[E + e]], 1);
}

__global__ __launch_bounds__(1024)
void scan_kernel(const int* __restrict__ cnt, int* __restrict__ starts, int N) {
  __shared__ int sums[1024];
  const int t = threadIdx.x;
  const int per = (N + 1023) >> 10;
  const int base = t * per;
  int s = 0;
  for (int i = 0; i < per; ++i) {
    const int idx = base + i;
    if (idx < N) s += cnt[idx];
  }
  sums[t] = s;
  __syncthreads();
  for (int off = 1; off < 1024; off <<= 1) {
    int v = (t >= off) ? sums[t - off] : 0;
    __syncthreads();
    sums[t] += v;
    __syncthreads();
  }
  int run = (t > 0) ? sums[t - 1] : 0;
  for (int i = 0; i < per; ++i) {
    const int idx = base + i;
    if (idx < N) { starts[idx] = run; run += cnt[idx]; }
  }
}

__global__ __launch_bounds__(256)
void scatter_kernel(const int* __restrict__ ei, const int* __restrict__ starts,
                    int* __restrict__ cursor, int* __restrict__ eperm, int E) {
  const int e = blockIdx.x * 256 + threadIdx.x;
  if (e < E) {
    const int d = ei[E + e];
    const int r = atomicAdd(&cursor[d], 1);
    eperm[starts[d] + r] = e;
  }
}

// ---------------- node embedding: node[:, :16] = mlp(x), geo = 0 ----------------
__global__ __launch_bounds__(256)
void emb_kernel(const float* __restrict__ x, const float* __restrict__ w0,
                const float* __restrict__ w1, float* __restrict__ node, int N) {
  const int lane = threadIdx.x & 63;
  const int lw   = threadIdx.x >> 6;
  const int gw   = blockIdx.x * 4 + lw;
  __shared__ float sH[4][64];
  const bool valid = gw < N;
  const int n = valid ? gw : 0;
  float acc = 0.f;
#pragma unroll
  for (int a = 0; a < 10; ++a) acc = fmaf(x[n * 10 + a], w0[a * 64 + lane], acc);
  acc *= 0.31622776601683794f;   // 1/sqrt(10)
  sH[lw][lane] = silu_n(acc);
  __syncthreads();
  if (valid) {
    if (lane < 16) {
      float o = 0.f;
#pragma unroll
      for (int k = 0; k < 64; ++k) o = fmaf(sH[lw][k], w1[k * 16 + lane], o);
      node[(size_t)n * 40 + lane] = o * 0.125f;  // 1/sqrt(64)
    } else if (lane < 40) {
      node[(size_t)n * 40 + lane] = 0.f;
    }
  }
}

// ---------------- node update (per mp step) with fused CSR message gather ----------
template <bool HALFMB>
__global__ __launch_bounds__(256)
void upd_kernel(float* __restrict__ node, const void* __restrict__ mbufv,
                const int* __restrict__ starts, const int* __restrict__ cnt,
                const int* __restrict__ eperm,
                const float* __restrict__ w0, const float* __restrict__ w1,
                const float* __restrict__ imp, float geo_scale, float inv_sqrt_deg, int N) {
  const int lane = threadIdx.x & 63;
  const int lw   = threadIdx.x >> 6;
  const int gw   = blockIdx.x * 4 + lw;
  __shared__ float sIn[4][32];
  __shared__ float sH[4][64];
  const bool valid = gw < N;
  const int n = valid ? gw : 0;
  const float mscale = imp[0] * inv_sqrt_deg;

  // gather message sum for this node (lanes 0..39 own the 40 columns)
  float m = 0.f;
  if (lane < 40) {
    const int s0 = starts[n], d = cnt[n];
    if (HALFMB) {
      const unsigned short* mb = (const unsigned short*)mbufv;
      for (int j = 0; j < d; ++j)
        m += h2f(mb[(size_t)eperm[s0 + j] * 40 + lane]);
    } else {
      const float* mb = (const float*)mbufv;
      for (int j = 0; j < d; ++j)
        m += mb[(size_t)eperm[s0 + j] * 40 + lane];
    }
  }

  if (lane < 16)      sIn[lw][lane] = m * mscale;
  else if (lane < 32) sIn[lw][lane] = node[(size_t)n * 40 + lane - 16];
  __syncthreads();
  float acc = 0.f;
#pragma unroll
  for (int a = 0; a < 32; ++a) acc = fmaf(sIn[lw][a], w0[a * 64 + lane], acc);
  acc *= 0.17677669529663687f;   // 1/sqrt(32)
  sH[lw][lane] = silu_n(acc);
  __syncthreads();
  if (valid) {
    if (lane < 16) {
      float o = 0.f;
#pragma unroll
      for (int k = 0; k < 64; ++k) o = fmaf(sH[lw][k], w1[k * 16 + lane], o);
      node[(size_t)n * 40 + lane] = o * 0.125f;
    } else if (lane < 40) {
      const size_t gi = (size_t)n * 40 + lane;
      node[gi] = fmaf(m, mscale, node[gi]) * geo_scale;
    }
  }
}

// ---------------- inter-edge: distance embedding -> both hidden vectors ----------------
__global__ __launch_bounds__(256)
void inter_h_kernel(const float* __restrict__ pos, const int* __restrict__ iei,
                    const float* __restrict__ lw0, const float* __restrict__ rw0,
                    float* __restrict__ hL, float* __restrict__ hR, int EI) {
  const int lane = threadIdx.x & 63;
  const int lw   = threadIdx.x >> 6;
  const int gw   = blockIdx.x * 4 + lw;
  __shared__ float sD[4][20];
  const bool valid = gw < EI;
  const int e = valid ? gw : 0;
  const int rec = iei[e], lig = iei[EI + e];
  const float dx = pos[lig * 3]     - pos[rec * 3];
  const float dy = pos[lig * 3 + 1] - pos[rec * 3 + 1];
  const float dz = pos[lig * 3 + 2] - pos[rec * 3 + 2];
  const float d = sqrtf(dx * dx + dy * dy + dz * dz);
  if (lane < 20) {
    const float diff = d * 4.2f - (float)(lane + 1);
    const float t1 = diff + 1.f, t2 = 1.f - diff;
    float v = 0.f;
    if (t1 > 0.f && t2 > 0.f) {
      const float C = 1.14136f * 7.3890560989306495f * 4.4721359549995794f; // 1.14136*e^2*sqrt(20)
      v = C * __expf(-1.f / t1 - 1.f / t2);
    }
    sD[lw][lane] = v;
  }
  __syncthreads();
  float a0 = 0.f, a1 = 0.f;
#pragma unroll
  for (int b = 0; b < 20; ++b) {
    const float db = sD[lw][b];
    a0 = fmaf(db, lw0[b * 64 + lane], a0);
    a1 = fmaf(db, rw0[b * 64 + lane], a1);
  }
  a0 *= 0.22360679774997896f;  // 1/sqrt(20)
  a1 *= 0.22360679774997896f;
  if (valid) {
    hL[(size_t)e * 64 + lane] = silu_n(a0);
    hR[(size_t)e * 64 + lane] = silu_n(a1);
  }
}

// ---------------- edge MLP layer for msg passes -> packed A-fragments ----------------
__global__ __launch_bounds__(256)
void edge_hf_kernel(const float* __restrict__ eattr, const float* __restrict__ w0,
                    uint4* __restrict__ hEf, int E, int nTe) {
  const int gid = blockIdx.x * 256 + threadIdx.x;
  if (gid >= nTe * 128) return;
  const int T = gid >> 7, rem = gid & 127, H = rem >> 6, l = rem & 63;
  int e = T * 16 + (l & 15);
  if (e >= E) e = E - 1;
  const int k0 = H * 32 + (l >> 4) * 8;
  float ea[5];
#pragma unroll
  for (int a = 0; a < 5; ++a) ea[a] = eattr[(size_t)e * 5 + a] * 0.4472135954999579f;
  unsigned q[4];
#pragma unroll
  for (int jj = 0; jj < 4; ++jj) {
    float hh[2];
#pragma unroll
    for (int p = 0; p < 2; ++p) {
      const int k = k0 + jj * 2 + p;
      float acc = 0.f;
#pragma unroll
      for (int a = 0; a < 5; ++a) acc = fmaf(ea[a], w0[a * 64 + k], acc);
      hh[p] = silu_n(acc);
    }
    q[jj] = packh2(hh[0], hh[1]);
  }
  uint4 out; out.x = q[0]; out.y = q[1]; out.z = q[2]; out.w = q[3];
  hEf[gid] = out;
}

// ---------------- msg pass: MFMA GEMM (h @ W1) + fused TP -> per-edge mbuf store ----
// Identical compute to round 13; the atomicAdd scatter is replaced by plain stores
// of the full 40-value per-edge message into mbuf[e*40 + col] (each slot written
// exactly once). upd_kernel gathers via CSR.
template <bool HALFMB>
__global__ __launch_bounds__(256, 2)
void msg_mfma_kernel(const float* __restrict__ node, const float* __restrict__ pos,
                     const int* __restrict__ ei, const float* __restrict__ W1,
                     const uint4* __restrict__ hEf, void* __restrict__ mbufv,
                     int E, int nTe) {
  __shared__ __align__(16) uint4 sB[36 * 128];              // 73728 B
  __shared__ __align__(16) unsigned short sFt[4][16][56];   //  7168 B -> 80896 total
  const int tid = threadIdx.x, lane = tid & 63, wv = tid >> 6;

  for (int j = tid; j < 4608; j += 256) {
    const int t = j >> 7, H = (j >> 6) & 1, l = j & 63;
    const int kb = H * 32 + (l >> 4) * 8;
    const float* src = &W1[(size_t)kb * 576 + t * 16 + (l & 15)];
    uint4 q;
    q.x = packh2(src[0],       src[576]);
    q.y = packh2(src[2 * 576], src[3 * 576]);
    q.z = packh2(src[4 * 576], src[5 * 576]);
    q.w = packh2(src[6 * 576], src[7 * 576]);
    sB[j] = q;
  }
  __syncthreads();

  unsigned short (*fW)[56] = sFt[wv];
  const int er0 = (lane >> 4) * 4;
  const int c   = lane & 15;
  const int cp  = (lane >> 3) & 1;
  const int w   = c & 7;

  for (int T = blockIdx.x * 4 + wv; T < nTe; T += (int)gridDim.x * 4) {
    // ---- prologue: per-wave feature staging (same-wave LDS RAW, no barrier) ----
    if (lane < 16) {                         // r-hat
      int ge = T * 16 + lane; if (ge >= E) ge = E - 1;
      const int ia = ei[ge], ib = ei[E + ge];
      const float vx = pos[ib * 3]     - pos[ia * 3];
      const float vy = pos[ib * 3 + 1] - pos[ia * 3 + 1];
      const float vz = pos[ib * 3 + 2] - pos[ia * 3 + 2];
      const float rn = rsqrtf(vx * vx + vy * vy + vz * vz);
      fW[lane][40] = f16bits(vx * rn);
      fW[lane][41] = f16bits(vy * rn);
      fW[lane][42] = f16bits(vz * rn);
    }
#pragma unroll
    for (int j = 0; j < 4; ++j) {            // xs: e = j*4+(lane>>4), u = c
      const int e = j * 4 + (lane >> 4);
      int ge = T * 16 + e; if (ge >= E) ge = E - 1;
      const int ns = ei[ge];
      fW[e][c] = f16bits(node[(size_t)ns * 40 + c]);
    }
#pragma unroll
    for (int j = 0; j < 6; ++j) {            // xv: flat = e*24 + (u*3+i)
      const int flat = j * 64 + lane;
      const int e = flat / 24, q = flat - e * 24;
      const int u = q / 3, i = q - u * 3;
      int ge = T * 16 + e; if (ge >= E) ge = E - 1;
      const int ns = ei[ge];
      fW[e][16 + i * 8 + (u & 1) * 4 + (u >> 1)] = f16bits(node[(size_t)ns * 40 + 16 + q]);
    }
#pragma unroll
    for (int j = 0; j < 2; ++j) {            // dotp[e][u] = sum_i xv*rhat
      const int flat = j * 64 + lane;
      const int e = flat >> 3, u = flat & 7;
      float d = 0.f;
#pragma unroll
      for (int i = 0; i < 3; ++i)
        d = fmaf(h2f(fW[e][16 + i * 8 + (u & 1) * 4 + (u >> 1)]), h2f(fW[e][40 + i]), d);
      fW[e][48 + u] = f16bits(d);
    }

    const uint4 a0 = hEf[T * 128 + lane];
    const uint4 a1 = hEf[T * 128 + 64 + lane];

    uint4 xsR[4][2], dpR[4];
    uint2 xvR[4][3];
    float rf[4][3];
#pragma unroll
    for (int r = 0; r < 4; ++r) {
      const int e = er0 + r;
      xsR[r][0] = *(const uint4*)&fW[e][0];
      xsR[r][1] = *(const uint4*)&fW[e][8];
      dpR[r]    = *(const uint4*)&fW[e][48];
#pragma unroll
      for (int i = 0; i < 3; ++i) {
        xvR[r][i] = *(const uint2*)&fW[e][16 + i * 8 + cp * 4];
        rf[r][i]  = h2f(fW[e][40 + i]);
      }
    }

    float o_s[4] = {0.f, 0.f, 0.f, 0.f};
    float sxw[4] = {0.f, 0.f, 0.f, 0.f};
    float ov[3][4];
#pragma unroll
    for (int i = 0; i < 3; ++i)
#pragma unroll
      for (int r = 0; r < 4; ++r) ov[i][r] = 0.f;

    uint4 b0 = sB[lane], b1 = sB[64 + lane];
#pragma unroll
    for (int t = 0; t < 36; ++t) {
      uint4 n0, n1;
      if (t < 35) { n0 = sB[(t + 1) * 128 + lane]; n1 = sB[(t + 1) * 128 + 64 + lane]; }
      f32x4 C = {0.f, 0.f, 0.f, 0.f};
      C = mfma16(a0, b0, C);
      C = mfma16(a1, b1, C);
      if (t < 16) {
#pragma unroll
        for (int r = 0; r < 4; ++r)
          o_s[r] = fmaf(hsel(u4sel(xsR[r][t >> 3], (t >> 1) & 3), t & 1), C[r], o_s[r]);
      } else if (t < 24) {
        const int u = t - 16;
#pragma unroll
        for (int r = 0; r < 4; ++r)
          o_s[r] = fmaf(hsel(u4sel(dpR[r], u >> 1), u & 1), C[r], o_s[r]);
      } else if (t < 32) {
        const int j = t - 24;  // u = 2j+cp
#pragma unroll
        for (int r = 0; r < 4; ++r) {
          const int idx = 2 * j + cp;
          sxw[r] = fmaf(hsel(u4sel(xsR[r][idx >> 3], (idx >> 1) & 3), idx & 1), C[r], sxw[r]);
        }
      } else {
        const int j = t - 32;  // u = 2j+cp
#pragma unroll
        for (int i = 0; i < 3; ++i)
#pragma unroll
          for (int r = 0; r < 4; ++r)
            ov[i][r] = fmaf(hsel(u2sel(xvR[r][i], j >> 1), j & 1), C[r], ov[i][r]);
      }
      if (t < 35) { b0 = n0; b1 = n1; }
    }

    // ---- write per-edge message (plain stores; every slot written once) ----
#pragma unroll
    for (int r = 0; r < 4; ++r) {
      const int ge = T * 16 + er0 + r;
      const bool valid = ge < E;
      const float sv = PW0s * o_s[r];
      float vv[3];
#pragma unroll
      for (int i = 0; i < 3; ++i) {
        float v = fmaf(PW1s * rf[r][i], sxw[r], PW0s * ov[i][r]);
        v += __shfl_xor(v, 8);
        vv[i] = v;
      }
      if (valid) {
        if (HALFMB) {
          unsigned short* mb = (unsigned short*)mbufv + (size_t)ge * 40;
          mb[c] = f16bits(sv);
          if ((lane & 8) == 0) {
#pragma unroll
            for (int i = 0; i < 3; ++i) mb[16 + w * 3 + i] = f16bits(vv[i]);
          }
        } else {
          float* mb = (float*)mbufv + (size_t)ge * 40;
          mb[c] = sv;
          if ((lane & 8) == 0) {
#pragma unroll
            for (int i = 0; i < 3; ++i) mb[16 + w * 3 + i] = vv[i];
          }
        }
      }
    }
  }
}

// ---------------- fused edge MLP (layer2) + node x sh tensor product (dot2) ---------
// Retained for MODE1 (lig TP) only — proven round-10 kernel.
template <int MODE>
__global__ __launch_bounds__(512, 2)
void tp_kernel(const float* __restrict__ node, const float* __restrict__ pos,
               const int* __restrict__ ei, const float* __restrict__ eattr,
               const float* __restrict__ w0, const float* __restrict__ W1,
               const float* __restrict__ hSrc, float* __restrict__ out, int E) {
  __shared__ __align__(16) uint4 sWa[32 * 64];
  __shared__ __align__(16) uint4 sWb[32 * 64];
  __shared__ unsigned sWc[32 * 64];
  __shared__ float sF[8][6][27];
  const int tid  = threadIdx.x;
  const int lane = tid & 63;
  const int wv   = tid >> 6;

  for (int j = tid; j < 2048; j += 512) {
    const int kp = j >> 6, l = j & 63;
    const float* s0 = &W1[(2 * kp) * 576 + l];
    const float* s1 = s0 + 576;
    uint4 qa, qb;
    qa.x = packh2(s0[0],   s1[0]);
    qa.y = packh2(s0[64],  s1[64]);
    qa.z = packh2(s0[128], s1[128]);
    qa.w = packh2(s0[192], s1[192]);
    qb.x = packh2(s0[256], s1[256]);
    qb.y = packh2(s0[320], s1[320]);
    qb.z = packh2(s0[384], s1[384]);
    qb.w = packh2(s0[448], s1[448]);
    sWa[j] = qa;
    sWb[j] = qb;
    sWc[j] = packh2(s0[512], s1[512]);
  }
  __syncthreads();

  float w0r[5];
  if (MODE == 0) {
#pragma unroll
    for (int a = 0; a < 5; ++a) w0r[a] = w0[a * 64 + lane] * 0.4472135954999579f;
  }
  const int kl2 = (lane & 31) * 2;

  const int nB = (E + 47) / 48;
  for (int b = blockIdx.x; b < nB; b += (int)gridDim.x) {
    const int ebase = b * 48 + wv * 6;
    int outn[6], nsrc[6];
    bool val[6];
    unsigned hp[6];
#pragma unroll
    for (int s = 0; s < 6; ++s) {
      const int e0 = ebase + s;
      val[s] = e0 < E;
      const int e = val[s] ? e0 : 0;
      const int ia = ei[e], ib = ei[E + e];
      if (MODE == 0) { nsrc[s] = ia; outn[s] = ib; }
      else           { nsrc[s] = ib; outn[s] = e;  }
      const float vx = pos[ib * 3]     - pos[ia * 3];
      const float vy = pos[ib * 3 + 1] - pos[ia * 3 + 1];
      const float vz = pos[ib * 3 + 2] - pos[ia * 3 + 2];
      const float rn = rsqrtf(vx * vx + vy * vy + vz * vz);
      const float rx = vx * rn, ry = vy * rn, rz = vz * rn;
      float h;
      if (MODE == 0) {
        float acc = 0.f;
#pragma unroll
        for (int a = 0; a < 5; ++a) acc = fmaf(eattr[(size_t)e * 5 + a], w0r[a], acc);
        h = silu_n(acc);
      } else {
        h = hSrc[(size_t)e * 64 + lane];
      }
      hp[s] = packh2(__shfl(h, kl2), __shfl(h, kl2 + 1));
      if (lane < 16) {
        sF[wv][s][lane] = node[(size_t)nsrc[s] * 40 + lane];
      } else if (lane < 24) {
        const int u = lane - 16;
        const float x0 = node[(size_t)nsrc[s] * 40 + 16 + u * 3];
        const float x1 = node[(size_t)nsrc[s] * 40 + 16 + u * 3 + 1];
        const float x2 = node[(size_t)nsrc[s] * 40 + 16 + u * 3 + 2];
        sF[wv][s][16 + u] = x0 * rx + x1 * ry + x2 * rz;
      } else if (lane < 27) {
        sF[wv][s][24 + (lane - 24)] = (lane == 24) ? rx : ((lane == 25) ? ry : rz);
      }
    }

    float wacc[6][9];
#pragma unroll
    for (int s = 0; s < 6; ++s)
#pragma unroll
      for (int t = 0; t < 9; ++t) wacc[s][t] = 0.f;

    uint4 qa0 = sWa[lane], qb0 = sWb[lane];
    unsigned qc0 = sWc[lane];
#pragma unroll 4
    for (int kp = 0; kp < 32; ++kp) {
      const int kn = (kp + 1) & 31;
      const uint4 qa1 = sWa[kn * 64 + lane];
      const uint4 qb1 = sWb[kn * 64 + lane];
      const unsigned qc1 = sWc[kn * 64 + lane];
#pragma unroll
      for (int s = 0; s < 6; ++s) {
        const unsigned hv2 = ubcast_lane(hp[s], kp);
        wacc[s][0] = dot2h(qa0.x, hv2, wacc[s][0]);
        wacc[s][1] = dot2h(qa0.y, hv2, wacc[s][1]);
        wacc[s][2] = dot2h(qa0.z, hv2, wacc[s][2]);
        wacc[s][3] = dot2h(qa0.w, hv2, wacc[s][3]);
        wacc[s][4] = dot2h(qb0.x, hv2, wacc[s][4]);
        wacc[s][5] = dot2h(qb0.y, hv2, wacc[s][5]);
        wacc[s][6] = dot2h(qb0.z, hv2, wacc[s][6]);
        wacc[s][7] = dot2h(qb0.w, hv2, wacc[s][7]);
        wacc[s][8] = dot2h(qc0,   hv2, wacc[s][8]);
      }
      qa0 = qa1; qb0 = qb1; qc0 = qc1;
    }

    const int ub  = lane >> 4;
    const int ub2 = lane >> 3;
#pragma unroll
    for (int s = 0; s < 6; ++s) {
      float cs = 0.f;
#pragma unroll
      for (int t = 0; t < 6; ++t)
        cs = fmaf(PW0s * sF[wv][s][ub + 4 * t], wacc[s][t], cs);
      cs += __shfl_xor(cs, 16);
      cs += __shfl_xor(cs, 32);

      const float rx = sF[wv][s][24], ry = sF[wv][s][25], rz = sF[wv][s][26];
      const float* xp = &node[(size_t)nsrc[s] * 40 + 16 + ub2 * 3];
      const float xv0 = xp[0], xv1 = xp[1], xv2 = xp[2];
      const float sxw = PW1s * (sF[wv][s][ub2] * wacc[s][6] + sF[wv][s][ub2 + 8] * wacc[s][7]);
      float cv0 = fmaf(PW0s * xv0, wacc[s][8], sxw * rx);
      float cv1 = fmaf(PW0s * xv1, wacc[s][8], sxw * ry);
      float cv2 = fmaf(PW0s * xv2, wacc[s][8], sxw * rz);
      cv0 += __shfl_xor(cv0, 8); cv0 += __shfl_xor(cv0, 16); cv0 += __shfl_xor(cv0, 32);
      cv1 += __shfl_xor(cv1, 8); cv1 += __shfl_xor(cv1, 16); cv1 += __shfl_xor(cv1, 32);
      cv2 += __shfl_xor(cv2, 8); cv2 += __shfl_xor(cv2, 16); cv2 += __shfl_xor(cv2, 32);

      if (val[s]) {
        const size_t ob = (size_t)outn[s] * 40;
        if (lane < 16) out[ob + lane] = cs;
        if (lane < 8) {
          out[ob + 16 + lane * 3]     = cv0;
          out[ob + 16 + lane * 3 + 1] = cv1;
          out[ob + 16 + lane * 3 + 2] = cv2;
        }
      }
    }
  }
}

// ---------------- pack hR into MFMA A-fragments (fp16) ----------------
__global__ __launch_bounds__(512)
void pack_h_kernel(const float* __restrict__ h, uint4* __restrict__ hPf, int nT) {
  const int gid = blockIdx.x * 512 + threadIdx.x;
  if (gid >= nT * 128) return;
  const int l = gid & 63;
  const int H = (gid >> 6) & 1;
  const int T = gid >> 7;
  const int e = T * 16 + (l & 15);
  const int kb = H * 32 + (l >> 4) * 8;
  const float* src = &h[(size_t)e * 64 + kb];
  uint4 q;
  q.x = packh2(src[0], src[1]);
  q.y = packh2(src[2], src[3]);
  q.z = packh2(src[4], src[5]);
  q.w = packh2(src[6], src[7]);
  hPf[gid] = q;
}

// ---------------- precompute vector-path dot table (fp16, parity-separated) --------
__global__ __launch_bounds__(256)
void pack_d_kernel(const float* __restrict__ ligE, const float* __restrict__ node,
                   const int* __restrict__ iei, unsigned short* __restrict__ Dt, int EI) {
  const int gid = blockIdx.x * 256 + threadIdx.x;
  if (gid >= EI * 64) return;
  const int e = gid >> 6, rem = gid & 63;
  const int b = rem >> 5, u = (rem >> 2) & 7, vi = rem & 3;
  const int v = 2 * vi + b;
  const int rec = iei[e];
  const float* xp = &ligE[(size_t)e * 40 + 16 + u * 3];
  const float* yp = &node[(size_t)rec * 40 + 16 + v * 3];
  const float d = (xp[0] * yp[0] + xp[1] * yp[1] + xp[2] * yp[2]) * INV_SQ3;
  Dt[gid] = f16bits(d);
}

// ---------------- rec: MFMA GEMM (h @ RW1 chunk) + fused TP epilogue ----------------
__global__ __launch_bounds__(512, 2)
void rec_kernel(const float* __restrict__ node, const float* __restrict__ ligE,
                const int* __restrict__ iei, const float* __restrict__ RW1,
                const uint4* __restrict__ hPf, const uint2* __restrict__ Dt2,
                float* __restrict__ out, int nT) {
  __shared__ __align__(16) uint4 sB[4096];
  __shared__ __align__(16) unsigned short sFeat[8][320];
  const int tid = threadIdx.x, lane = tid & 63, wv = tid >> 6;
  const int cg = blockIdx.y;

  for (int j = tid; j < 4096; j += 512) {
    const int t = j >> 7, H = (j >> 6) & 1, l = j & 63;
    const int kb = H * 32 + (l >> 4) * 8;
    const float* src = &RW1[(size_t)kb * 2560 + cg * 512 + t * 16 + (l & 15)];
    uint4 q;
    q.x = packh2(src[0],        src[2560]);
    q.y = packh2(src[2 * 2560], src[3 * 2560]);
    q.z = packh2(src[4 * 2560], src[5 * 2560]);
    q.w = packh2(src[6 * 2560], src[7 * 2560]);
    sB[j] = q;
  }
  __syncthreads();

  unsigned short* fW = sFeat[wv];
  const int er0 = (lane >> 4) * 4;
  const int bpar = (lane >> 3) & 1;
  const int c    = lane & 7;
  const int se = lane >> 2, si = lane & 3;

  for (int T = blockIdx.x * 8 + wv; T < nT; T += (int)gridDim.x * 8) {
    const uint4 a0 = hPf[(T * 2 + 0) * 64 + lane];
    const uint4 a1 = hPf[(T * 2 + 1) * 64 + lane];
    const int eg = T * 16 + se;

    if (cg < 4) {
      const int rn = iei[eg];
      const float4 yv = *(const float4*)&node[(size_t)rn * 40 + si * 4];
      *(unsigned*)&fW[(se * 2 + 0) * 8 + 2 * si] = packh2(yv.x, yv.z);
      *(unsigned*)&fW[(se * 2 + 1) * 8 + 2 * si] = packh2(yv.y, yv.w);
      fW[256 + se * 4 + si] = f16bits(ligE[(size_t)eg * 40 + cg * 4 + si]);
    }

    float o[4] = {0.f, 0.f, 0.f, 0.f};
    uint4 b0 = sB[lane], b1 = sB[64 + lane];

    if (cg < 4) {
      uint2 xsR[4]; uint4 ysR[4];
#pragma unroll
      for (int r = 0; r < 4; ++r) {
        const int er = er0 + r;
        ysR[r] = *(const uint4*)&fW[(er * 2 + bpar) * 8];
        xsR[r] = *(const uint2*)&fW[256 + er * 4];
      }
#pragma unroll
      for (int t = 0; t < 32; ++t) {
        uint4 n0, n1;
        if (t < 31) { n0 = sB[(t + 1) * 128 + lane]; n1 = sB[(t + 1) * 128 + 64 + lane]; }
        f32x4 C = {0.f, 0.f, 0.f, 0.f};
        C = mfma16(a0, b0, C);
        C = mfma16(a1, b1, C);
        const int up = t >> 3, vi = t & 7;
#pragma unroll
        for (int r = 0; r < 4; ++r) {
          const float xs = hsel(u2sel(xsR[r], up >> 1), up & 1);
          const float ys = hsel(u4sel(ysR[r], vi >> 1), vi & 1);
          o[r] = fmaf(xs * ys, C[r], o[r]);
        }
        if (t < 31) { b0 = n0; b1 = n1; }
      }
    } else {
#pragma unroll
      for (int pass = 0; pass < 2; ++pass) {
        uint2 dR[4][4];
#pragma unroll
        for (int r = 0; r < 4; ++r) {
          const int e = T * 16 + er0 + r;
#pragma unroll
          for (int uu = 0; uu < 4; ++uu)
            dR[r][uu] = Dt2[(size_t)e * 16 + bpar * 8 + pass * 4 + uu];
        }
#pragma unroll
        for (int tt = 0; tt < 16; ++tt) {
          const int t = pass * 16 + tt;
          uint4 n0, n1;
          if (t < 31) { n0 = sB[(t + 1) * 128 + lane]; n1 = sB[(t + 1) * 128 + 64 + lane]; }
          f32x4 C = {0.f, 0.f, 0.f, 0.f};
          C = mfma16(a0, b0, C);
          C = mfma16(a1, b1, C);
          const int uu = tt >> 2, vi = tt & 3;
#pragma unroll
          for (int r = 0; r < 4; ++r) {
            const float f = hsel(u2sel(dR[r][uu], vi >> 1), vi & 1);
            o[r] = fmaf(f, C[r], o[r]);
          }
          if (t < 31) { b0 = n0; b1 = n1; }
        }
      }
    }

#pragma unroll
    for (int r = 0; r < 4; ++r) {
      const float v = o[r] + __shfl_xor(o[r], 8);
      if ((lane & 8) == 0)
        atomicAdd(&out[(size_t)(T * 16 + er0 + r) * 8 + c], v * PWRECs);
    }
  }
}

extern "C" void kernel_launch(void* const* d_in, const int* in_sizes, int n_in,
                              void* d_out, int out_size, void* d_ws, size_t ws_size,
                              hipStream_t stream) {
  (void)n_in;
  const float* x      = (const float*)d_in[0];
  const float* pos    = (const float*)d_in[1];
  const int*   ei     = (const int*)  d_in[2];
  const float* eattr  = (const float*)d_in[3];
  const int*   iei    = (const int*)  d_in[4];
  const float* emb_w0 = (const float*)d_in[5];
  const float* emb_w1 = (const float*)d_in[6];
  const float* imp0   = (const float*)d_in[7];
  const float* m0w0   = (const float*)d_in[8];
  const float* m0w1   = (const float*)d_in[9];
  const float* u0w0   = (const float*)d_in[10];
  const float* u0w1   = (const float*)d_in[11];
  const float* imp1   = (const float*)d_in[12];
  const float* m1w0   = (const float*)d_in[13];
  const float* m1w1   = (const float*)d_in[14];
  const float* u1w0   = (const float*)d_in[15];
  const float* u1w1   = (const float*)d_in[16];
  const float* lw0    = (const float*)d_in[17];
  const float* lw1    = (const float*)d_in[18];
  const float* rw0    = (const float*)d_in[19];
  const float* rw1    = (const float*)d_in[20];

  const int N  = in_sizes[1] / 3;
  const int E  = in_sizes[2] / 2;
  const int EI = in_sizes[4] / 2;

  // ---- persistent layout (28.5 MB; previous rounds proved ws >= 30 MB) ----
  float* node = (float*)d_ws;                        // N*40
  float* hL   = node + (size_t)N * 40;               // EI*64
  float* hR   = hL + (size_t)EI * 64;                // EI*64
  float* ligE = hR + (size_t)EI * 64;                // EI*40
  float* outp = (float*)d_out;

  // ---- msg-phase overlay in hL..ligE region ----
  uint4* hEf   = (uint4*)hL;                         // E*32 floats (A-fragments)
  float* mbase = hL + (size_t)E * 32;                // mbuf region start
  // fp32 mbuf if workspace allows, else fp16 (fits inside proven footprint)
  const size_t csrInts = (size_t)3 * N + E + 16;
  const size_t need32  = ((size_t)N * 40 + (size_t)E * 32 + (size_t)E * 40 + csrInts) * 4;
  const bool   halfmb  = need32 > ws_size;
  const size_t mbFl    = halfmb ? ((size_t)E * 20) : ((size_t)E * 40);
  void* mbuf   = (void*)mbase;
  int*  cnt    = (int*)(mbase + mbFl);
  int*  starts = cnt + N;
  int*  cursor = starts + N;
  int*  eperm  = cursor + N;

  // ---- inter-phase overlays (after msg phase is done) ----
  uint4*          hPf = (uint4*)hL;
  unsigned short* Dt  = (unsigned short*)hR;

  const float inv_sqrt_deg = 1.0f / sqrtf((float)E / (float)N);
  const int nodeBlocks  = (N + 3) / 4;
  const int interBlocks = (EI + 3) / 4;
  const int nT  = EI / 16;             // 2500 (EI divisible by 16)
  const int nTe = (E + 15) / 16;       // 7500
  const int hfBlocks = (nTe * 128 + 255) / 256;
  const int eBlocks  = (E + 255) / 256;

  // ---- CSR build (once; edge_index shared by both msg passes) ----
  hipMemsetAsync(cnt, 0, (size_t)N * sizeof(int), stream);
  hipMemsetAsync(cursor, 0, (size_t)N * sizeof(int), stream);
  hist_kernel<<<eBlocks, 256, 0, stream>>>(ei, cnt, E);
  scan_kernel<<<1, 1024, 0, stream>>>(cnt, starts, N);
  scatter_kernel<<<eBlocks, 256, 0, stream>>>(ei, starts, cursor, eperm, E);

  emb_kernel<<<nodeBlocks, 256, 0, stream>>>(x, emb_w0, emb_w1, node, N);

  // message pass 0
  edge_hf_kernel<<<hfBlocks, 256, 0, stream>>>(eattr, m0w0, hEf, E, nTe);
  if (halfmb) {
    msg_mfma_kernel<true><<<512, 256, 0, stream>>>(node, pos, ei, m0w1, hEf, mbuf, E, nTe);
    upd_kernel<true><<<nodeBlocks, 256, 0, stream>>>(node, mbuf, starts, cnt, eperm,
                                                     u0w0, u0w1, imp0, 1.0f, inv_sqrt_deg, N);
  } else {
    msg_mfma_kernel<false><<<512, 256, 0, stream>>>(node, pos, ei, m0w1, hEf, mbuf, E, nTe);
    upd_kernel<false><<<nodeBlocks, 256, 0, stream>>>(node, mbuf, starts, cnt, eperm,
                                                      u0w0, u0w1, imp0, 1.0f, inv_sqrt_deg, N);
  }

  // message pass 1
  edge_hf_kernel<<<hfBlocks, 256, 0, stream>>>(eattr, m1w0, hEf, E, nTe);
  if (halfmb) {
    msg_mfma_kernel<true><<<512, 256, 0, stream>>>(node, pos, ei, m1w1, hEf, mbuf, E, nTe);
    upd_kernel<true><<<nodeBlocks, 256, 0, stream>>>(node, mbuf, starts, cnt, eperm,
                                                     u1w0, u1w1, imp1, 0.5f, inv_sqrt_deg, N);
  } else {
    msg_mfma_kernel<false><<<512, 256, 0, stream>>>(node, pos, ei, m1w1, hEf, mbuf, E, nTe);
    upd_kernel<false><<<nodeBlocks, 256, 0, stream>>>(node, mbuf, starts, cnt, eperm,
                                                      u1w0, u1w1, imp1, 0.5f, inv_sqrt_deg, N);
  }

  // inter edges
  inter_h_kernel<<<interBlocks, 256, 0, stream>>>(pos, iei, lw0, rw0, hL, hR, EI);
  tp_kernel<1><<<512, 512, 0, stream>>>(node, pos, iei, nullptr, nullptr, lw1, hL, ligE, EI);

  // pack A-fragments (reads hR, writes over hL) and D-table (writes over hR)
  pack_h_kernel<<<(nT * 128 + 511) / 512, 512, 0, stream>>>(hR, hPf, nT);
  pack_d_kernel<<<(EI * 64 + 255) / 256, 256, 0, stream>>>(ligE, node, iei, Dt, EI);

  hipMemsetAsync(outp, 0, (size_t)out_size * sizeof(float), stream);
  rec_kernel<<<dim3(102, 5), 512, 0, stream>>>(node, ligE, iei, rw1, hPf, (const uint2*)Dt,
                                               outp, nT);
}

// Round 15
// 381.701 us; speedup vs baseline: 1.0150x; 1.0150x over previous
//
#include <hip/hip_runtime.h>
#include <hip/hip_fp16.h>
#include <cmath>

// ---- constants from the reference ----
constexpr float ACT_NORM = 1.6789717f;
constexpr float PW0      = 0.20412414523193154f;   // sqrt(1/24)  (== pw1/sqrt3)
constexpr float PW1      = 0.35355339059327373f;   // sqrt(3/24)
constexpr float PWREC    = 0.05590169943749474f;   // sqrt(1/320)
constexpr float INV_SQ3  = 0.57735026918962576f;
// second-layer 1/sqrt(64) folded into epilogue constants
constexpr float PW0s     = PW0 * 0.125f;
constexpr float PW1s     = PW1 * 0.125f;
constexpr float PWRECs   = PWREC * 0.125f;

__device__ __forceinline__ float silu_n(float x) {
  return x / (1.f + __expf(-x)) * ACT_NORM;
}

__device__ __forceinline__ unsigned ubcast_lane(unsigned v, int k) {
  return (unsigned)__builtin_amdgcn_readlane((int)v, k);
}

// fp16 helpers
typedef _Float16 h2v __attribute__((ext_vector_type(2)));
typedef _Float16 f16x8 __attribute__((ext_vector_type(8)));
typedef float    f32x4 __attribute__((ext_vector_type(4)));

__device__ __forceinline__ unsigned packh2(float a, float b) {
  h2v p; p.x = (_Float16)a; p.y = (_Float16)b;
  return __builtin_bit_cast(unsigned, p);
}
__device__ __forceinline__ unsigned short f16bits(float a) {
  return __builtin_bit_cast(unsigned short, (_Float16)a);
}
__device__ __forceinline__ float h2f(unsigned short b) {
  return (float)__builtin_bit_cast(_Float16, b);
}
__device__ __forceinline__ float dot2h(unsigned w2, unsigned h2, float acc) {
  return __builtin_amdgcn_fdot2(__builtin_bit_cast(h2v, w2),
                                __builtin_bit_cast(h2v, h2), acc, false);
}
__device__ __forceinline__ float hlo(unsigned d) {
  return (float)__builtin_bit_cast(_Float16, (unsigned short)(d & 0xffffu));
}
__device__ __forceinline__ float hhi(unsigned d) {
  return (float)__builtin_bit_cast(_Float16, (unsigned short)(d >> 16));
}
__device__ __forceinline__ float hsel(unsigned d, int hi) { return hi ? hhi(d) : hlo(d); }
__device__ __forceinline__ unsigned u4sel(const uint4& v, int i) {
  return i == 0 ? v.x : (i == 1 ? v.y : (i == 2 ? v.z : v.w));
}
__device__ __forceinline__ unsigned u2sel(const uint2& v, int i) { return i ? v.y : v.x; }

// mfma_f32_16x16x32_f16: A row = lane&15; B col = lane&15 (consistent k grouping);
// C/D: col=lane&15, row=(lane>>4)*4+reg [HW-verified; proven rounds 12-14].
__device__ __forceinline__ f32x4 mfma16(uint4 a, uint4 b, f32x4 c) {
  return __builtin_amdgcn_mfma_f32_16x16x32_f16(
      __builtin_bit_cast(f16x8, a), __builtin_bit_cast(f16x8, b), c, 0, 0, 0);
}

// ---------------- CSR build: histogram -> block scan -> scatter ----------------
__global__ __launch_bounds__(256)
void hist_kernel(const int* __restrict__ ei, int* __restrict__ cnt, int E) {
  const int e = blockIdx.x * 256 + threadIdx.x;
  if (e < E) atomicAdd(&cnt[ei[E + e]], 1);
}

__global__ __launch_bounds__(1024)
void scan_kernel(const int* __restrict__ cnt, int* __restrict__ starts, int N) {
  __shared__ int sums[1024];
  const int t = threadIdx.x;
  const int per = (N + 1023) >> 10;
  const int base = t * per;
  int s = 0;
  for (int i = 0; i < per; ++i) {
    const int idx = base + i;
    if (idx < N) s += cnt[idx];
  }
  sums[t] = s;
  __syncthreads();
  for (int off = 1; off < 1024; off <<= 1) {
    int v = (t >= off) ? sums[t - off] : 0;
    __syncthreads();
    sums[t] += v;
    __syncthreads();
  }
  int run = (t > 0) ? sums[t - 1] : 0;
  for (int i = 0; i < per; ++i) {
    const int idx = base + i;
    if (idx < N) { starts[idx] = run; run += cnt[idx]; }
  }
}

__global__ __launch_bounds__(256)
void scatter_kernel(const int* __restrict__ ei, const int* __restrict__ starts,
                    int* __restrict__ cursor, int* __restrict__ eperm, int E) {
  const int e = blockIdx.x * 256 + threadIdx.x;
  if (e < E) {
    const int d = ei[E + e];
    const int r = atomicAdd(&cursor[d], 1);
    eperm[starts[d] + r] = e;
  }
}

// ---------------- pack W1 -> MFMA B-fragment table (fp16) ----------------
// Bp[t*128 + H*64 + l] = 8 fp16 of W1[kb..kb+7][t*16+(l&15)], kb = H*32+(l>>4)*8
__global__ __launch_bounds__(256)
void pack_b_kernel(const float* __restrict__ W1, uint4* __restrict__ Bp) {
  const int gid = blockIdx.x * 256 + threadIdx.x;
  if (gid >= 36 * 128) return;
  const int t = gid >> 7, H = (gid >> 6) & 1, l = gid & 63;
  const int kb = H * 32 + (l >> 4) * 8;
  const float* src = &W1[(size_t)kb * 576 + t * 16 + (l & 15)];
  uint4 q;
  q.x = packh2(src[0],       src[576]);
  q.y = packh2(src[2 * 576], src[3 * 576]);
  q.z = packh2(src[4 * 576], src[5 * 576]);
  q.w = packh2(src[6 * 576], src[7 * 576]);
  Bp[gid] = q;
}

// ---------------- node embedding: node[:, :16] = mlp(x), geo = 0 ----------------
__global__ __launch_bounds__(256)
void emb_kernel(const float* __restrict__ x, const float* __restrict__ w0,
                const float* __restrict__ w1, float* __restrict__ node, int N) {
  const int lane = threadIdx.x & 63;
  const int lw   = threadIdx.x >> 6;
  const int gw   = blockIdx.x * 4 + lw;
  __shared__ float sH[4][64];
  const bool valid = gw < N;
  const int n = valid ? gw : 0;
  float acc = 0.f;
#pragma unroll
  for (int a = 0; a < 10; ++a) acc = fmaf(x[n * 10 + a], w0[a * 64 + lane], acc);
  acc *= 0.31622776601683794f;   // 1/sqrt(10)
  sH[lw][lane] = silu_n(acc);
  __syncthreads();
  if (valid) {
    if (lane < 16) {
      float o = 0.f;
#pragma unroll
      for (int k = 0; k < 64; ++k) o = fmaf(sH[lw][k], w1[k * 16 + lane], o);
      node[(size_t)n * 40 + lane] = o * 0.125f;  // 1/sqrt(64)
    } else if (lane < 40) {
      node[(size_t)n * 40 + lane] = 0.f;
    }
  }
}

// ---------------- node update (per mp step) with fused CSR message gather ----------
__global__ __launch_bounds__(256)
void upd_kernel(float* __restrict__ node, const float* __restrict__ mbuf,
                const int* __restrict__ starts, const int* __restrict__ cnt,
                const int* __restrict__ eperm,
                const float* __restrict__ w0, const float* __restrict__ w1,
                const float* __restrict__ imp, float geo_scale, float inv_sqrt_deg, int N) {
  const int lane = threadIdx.x & 63;
  const int lw   = threadIdx.x >> 6;
  const int gw   = blockIdx.x * 4 + lw;
  __shared__ float sIn[4][32];
  __shared__ float sH[4][64];
  const bool valid = gw < N;
  const int n = valid ? gw : 0;
  const float mscale = imp[0] * inv_sqrt_deg;

  // gather message sum for this node (lanes 0..39 own the 40 columns)
  float m = 0.f;
  if (lane < 40) {
    const int s0 = starts[n], d = cnt[n];
    for (int j = 0; j < d; ++j)
      m += mbuf[(size_t)eperm[s0 + j] * 40 + lane];
  }

  if (lane < 16)      sIn[lw][lane] = m * mscale;
  else if (lane < 32) sIn[lw][lane] = node[(size_t)n * 40 + lane - 16];
  __syncthreads();
  float acc = 0.f;
#pragma unroll
  for (int a = 0; a < 32; ++a) acc = fmaf(sIn[lw][a], w0[a * 64 + lane], acc);
  acc *= 0.17677669529663687f;   // 1/sqrt(32)
  sH[lw][lane] = silu_n(acc);
  __syncthreads();
  if (valid) {
    if (lane < 16) {
      float o = 0.f;
#pragma unroll
      for (int k = 0; k < 64; ++k) o = fmaf(sH[lw][k], w1[k * 16 + lane], o);
      node[(size_t)n * 40 + lane] = o * 0.125f;
    } else if (lane < 40) {
      const size_t gi = (size_t)n * 40 + lane;
      node[gi] = fmaf(m, mscale, node[gi]) * geo_scale;
    }
  }
}

// ---------------- inter-edge: distance embedding -> both hidden vectors ----------------
__global__ __launch_bounds__(256)
void inter_h_kernel(const float* __restrict__ pos, const int* __restrict__ iei,
                    const float* __restrict__ lw0, const float* __restrict__ rw0,
                    float* __restrict__ hL, float* __restrict__ hR, int EI) {
  const int lane = threadIdx.x & 63;
  const int lw   = threadIdx.x >> 6;
  const int gw   = blockIdx.x * 4 + lw;
  __shared__ float sD[4][20];
  const bool valid = gw < EI;
  const int e = valid ? gw : 0;
  const int rec = iei[e], lig = iei[EI + e];
  const float dx = pos[lig * 3]     - pos[rec * 3];
  const float dy = pos[lig * 3 + 1] - pos[rec * 3 + 1];
  const float dz = pos[lig * 3 + 2] - pos[rec * 3 + 2];
  const float d = sqrtf(dx * dx + dy * dy + dz * dz);
  if (lane < 20) {
    const float diff = d * 4.2f - (float)(lane + 1);
    const float t1 = diff + 1.f, t2 = 1.f - diff;
    float v = 0.f;
    if (t1 > 0.f && t2 > 0.f) {
      const float C = 1.14136f * 7.3890560989306495f * 4.4721359549995794f; // 1.14136*e^2*sqrt(20)
      v = C * __expf(-1.f / t1 - 1.f / t2);
    }
    sD[lw][lane] = v;
  }
  __syncthreads();
  float a0 = 0.f, a1 = 0.f;
#pragma unroll
  for (int b = 0; b < 20; ++b) {
    const float db = sD[lw][b];
    a0 = fmaf(db, lw0[b * 64 + lane], a0);
    a1 = fmaf(db, rw0[b * 64 + lane], a1);
  }
  a0 *= 0.22360679774997896f;  // 1/sqrt(20)
  a1 *= 0.22360679774997896f;
  if (valid) {
    hL[(size_t)e * 64 + lane] = silu_n(a0);
    hR[(size_t)e * 64 + lane] = silu_n(a1);
  }
}

// ---------------- msg pass: inline-h MFMA GEMM (h @ W1) + fused TP -> fp32 mbuf ----
// h computed in-kernel: lane k=lane column, 16 edges, silu into fW[e][k] (fp16),
// then A-fragments read back as 2x ds_read_b128. B ntiles 0..31 staged in LDS from
// the packed Bp table; ntiles 32..35 held in 8 uint4 regs (T-invariant, hoisted).
// Per-edge message written with plain fp32 dword stores (each slot exactly once).
__global__ __launch_bounds__(256, 2)
void msg_mfma_kernel(const float* __restrict__ node, const float* __restrict__ pos,
                     const int* __restrict__ ei, const float* __restrict__ eattr,
                     const float* __restrict__ w0, const uint4* __restrict__ Bp,
                     float* __restrict__ mbuf, int E, int nTe) {
  __shared__ __align__(16) uint4 sB[32 * 128];              // 65536 B: ntiles 0..31
  __shared__ __align__(16) unsigned short sFt[4][16][64];   //  8192 B -> 73728 total
  const int tid = threadIdx.x, lane = tid & 63, wv = tid >> 6;

  for (int j = tid; j < 4096; j += 256) sB[j] = Bp[j];
  __syncthreads();

  // ntiles 32..35 in registers (do not depend on T)
  uint4 g32[8];
#pragma unroll
  for (int j = 0; j < 8; ++j) g32[j] = Bp[(64 + j) * 64 + lane];

  // w0 column for this lane's k (1/sqrt(5) folded)
  float w0c[5];
#pragma unroll
  for (int a = 0; a < 5; ++a) w0c[a] = w0[a * 64 + lane] * 0.4472135954999579f;

  unsigned short (*fW)[64] = sFt[wv];
  const int er0 = (lane >> 4) * 4;
  const int c   = lane & 15;
  const int cp  = (lane >> 3) & 1;
  const int w   = c & 7;
  const int el  = lane & 15;
  const int kb0 = (lane >> 4) * 8;

  for (int T = blockIdx.x * 4 + wv; T < nTe; T += (int)gridDim.x * 4) {
    // ---- (1) stage eattr tile into fW[e][56..60] (fp16; same-wave LDS RAW) ----
#pragma unroll
    for (int j = 0; j < 2; ++j) {
      const int flat = j * 64 + lane;
      if (flat < 80) {
        const int e = flat / 5, a = flat - e * 5;
        int ge = T * 16 + e; if (ge >= E) ge = E - 1;
        fW[e][56 + a] = f16bits(eattr[(size_t)ge * 5 + a]);
      }
    }
    // ---- (2) h: lane owns column k=lane; silu over 16 edges -> fW[e][lane] ----
#pragma unroll
    for (int e = 0; e < 16; ++e) {
      float acc = 0.f;
#pragma unroll
      for (int a = 0; a < 5; ++a) acc = fmaf(h2f(fW[e][56 + a]), w0c[a], acc);
      fW[e][lane] = f16bits(silu_n(acc));
    }
    // ---- (3) A-fragments from LDS (2x b128; 16-way conflict accepted) ----
    const uint4 a0 = *(const uint4*)&fW[el][kb0];
    const uint4 a1 = *(const uint4*)&fW[el][32 + kb0];

    // ---- (4) feature staging (overwrites h region; a0/a1 already in regs) ----
    if (lane < 16) {                         // r-hat
      int ge = T * 16 + lane; if (ge >= E) ge = E - 1;
      const int ia = ei[ge], ib = ei[E + ge];
      const float vx = pos[ib * 3]     - pos[ia * 3];
      const float vy = pos[ib * 3 + 1] - pos[ia * 3 + 1];
      const float vz = pos[ib * 3 + 2] - pos[ia * 3 + 2];
      const float rn = rsqrtf(vx * vx + vy * vy + vz * vz);
      fW[lane][40] = f16bits(vx * rn);
      fW[lane][41] = f16bits(vy * rn);
      fW[lane][42] = f16bits(vz * rn);
    }
#pragma unroll
    for (int j = 0; j < 4; ++j) {            // xs: e = j*4+(lane>>4), u = c
      const int e = j * 4 + (lane >> 4);
      int ge = T * 16 + e; if (ge >= E) ge = E - 1;
      const int ns = ei[ge];
      fW[e][c] = f16bits(node[(size_t)ns * 40 + c]);
    }
#pragma unroll
    for (int j = 0; j < 6; ++j) {            // xv: flat = e*24 + (u*3+i)
      const int flat = j * 64 + lane;
      const int e = flat / 24, q = flat - e * 24;
      const int u = q / 3, i = q - u * 3;
      int ge = T * 16 + e; if (ge >= E) ge = E - 1;
      const int ns = ei[ge];
      fW[e][16 + i * 8 + (u & 1) * 4 + (u >> 1)] = f16bits(node[(size_t)ns * 40 + 16 + q]);
    }
#pragma unroll
    for (int j = 0; j < 2; ++j) {            // dotp[e][u] = sum_i xv*rhat
      const int flat = j * 64 + lane;
      const int e = flat >> 3, u = flat & 7;
      float d = 0.f;
#pragma unroll
      for (int i = 0; i < 3; ++i)
        d = fmaf(h2f(fW[e][16 + i * 8 + (u & 1) * 4 + (u >> 1)]), h2f(fW[e][40 + i]), d);
      fW[e][48 + u] = f16bits(d);
    }

    uint4 xsR[4][2], dpR[4];
    uint2 xvR[4][3];
    float rf[4][3];
#pragma unroll
    for (int r = 0; r < 4; ++r) {
      const int e = er0 + r;
      xsR[r][0] = *(const uint4*)&fW[e][0];
      xsR[r][1] = *(const uint4*)&fW[e][8];
      dpR[r]    = *(const uint4*)&fW[e][48];
#pragma unroll
      for (int i = 0; i < 3; ++i) {
        xvR[r][i] = *(const uint2*)&fW[e][16 + i * 8 + cp * 4];
        rf[r][i]  = h2f(fW[e][40 + i]);
      }
    }

    float o_s[4] = {0.f, 0.f, 0.f, 0.f};
    float sxw[4] = {0.f, 0.f, 0.f, 0.f};
    float ov[3][4];
#pragma unroll
    for (int i = 0; i < 3; ++i)
#pragma unroll
      for (int r = 0; r < 4; ++r) ov[i][r] = 0.f;

    uint4 b0 = sB[lane], b1 = sB[64 + lane];
#pragma unroll
    for (int t = 0; t < 32; ++t) {
      uint4 n0, n1;
      if (t < 31) { n0 = sB[(t + 1) * 128 + lane]; n1 = sB[(t + 1) * 128 + 64 + lane]; }
      f32x4 C = {0.f, 0.f, 0.f, 0.f};
      C = mfma16(a0, b0, C);
      C = mfma16(a1, b1, C);
      if (t < 16) {
#pragma unroll
        for (int r = 0; r < 4; ++r)
          o_s[r] = fmaf(hsel(u4sel(xsR[r][t >> 3], (t >> 1) & 3), t & 1), C[r], o_s[r]);
      } else if (t < 24) {
        const int u = t - 16;
#pragma unroll
        for (int r = 0; r < 4; ++r)
          o_s[r] = fmaf(hsel(u4sel(dpR[r], u >> 1), u & 1), C[r], o_s[r]);
      } else {
        const int j = t - 24;  // u = 2j+cp
#pragma unroll
        for (int r = 0; r < 4; ++r) {
          const int idx = 2 * j + cp;
          sxw[r] = fmaf(hsel(u4sel(xsR[r][idx >> 3], (idx >> 1) & 3), idx & 1), C[r], sxw[r]);
        }
      }
      if (t < 31) { b0 = n0; b1 = n1; }
    }
#pragma unroll
    for (int j = 0; j < 4; ++j) {            // ntiles 32..35 from registers
      f32x4 C = {0.f, 0.f, 0.f, 0.f};
      C = mfma16(a0, g32[j * 2], C);
      C = mfma16(a1, g32[j * 2 + 1], C);
#pragma unroll
      for (int i = 0; i < 3; ++i)
#pragma unroll
        for (int r = 0; r < 4; ++r)
          ov[i][r] = fmaf(hsel(u2sel(xvR[r][i], j >> 1), j & 1), C[r], ov[i][r]);
    }

    // ---- write per-edge message (plain fp32 stores; every slot once) ----
#pragma unroll
    for (int r = 0; r < 4; ++r) {
      const int ge = T * 16 + er0 + r;
      const bool valid = ge < E;
      const float sv = PW0s * o_s[r];
      float vv[3];
#pragma unroll
      for (int i = 0; i < 3; ++i) {
        float v = fmaf(PW1s * rf[r][i], sxw[r], PW0s * ov[i][r]);
        v += __shfl_xor(v, 8);
        vv[i] = v;
      }
      if (valid) {
        float* mb = mbuf + (size_t)ge * 40;
        mb[c] = sv;
        if ((lane & 8) == 0) {
#pragma unroll
          for (int i = 0; i < 3; ++i) mb[16 + w * 3 + i] = vv[i];
        }
      }
    }
  }
}

// ---------------- fused edge MLP (layer2) + node x sh tensor product (dot2) ---------
// Retained for MODE1 (lig TP) only — proven round-10 kernel.
template <int MODE>
__global__ __launch_bounds__(512, 2)
void tp_kernel(const float* __restrict__ node, const float* __restrict__ pos,
               const int* __restrict__ ei, const float* __restrict__ eattr,
               const float* __restrict__ w0, const float* __restrict__ W1,
               const float* __restrict__ hSrc, float* __restrict__ out, int E) {
  __shared__ __align__(16) uint4 sWa[32 * 64];
  __shared__ __align__(16) uint4 sWb[32 * 64];
  __shared__ unsigned sWc[32 * 64];
  __shared__ float sF[8][6][27];
  const int tid  = threadIdx.x;
  const int lane = tid & 63;
  const int wv   = tid >> 6;

  for (int j = tid; j < 2048; j += 512) {
    const int kp = j >> 6, l = j & 63;
    const float* s0 = &W1[(2 * kp) * 576 + l];
    const float* s1 = s0 + 576;
    uint4 qa, qb;
    qa.x = packh2(s0[0],   s1[0]);
    qa.y = packh2(s0[64],  s1[64]);
    qa.z = packh2(s0[128], s1[128]);
    qa.w = packh2(s0[192], s1[192]);
    qb.x = packh2(s0[256], s1[256]);
    qb.y = packh2(s0[320], s1[320]);
    qb.z = packh2(s0[384], s1[384]);
    qb.w = packh2(s0[448], s1[448]);
    sWa[j] = qa;
    sWb[j] = qb;
    sWc[j] = packh2(s0[512], s1[512]);
  }
  __syncthreads();

  float w0r[5];
  if (MODE == 0) {
#pragma unroll
    for (int a = 0; a < 5; ++a) w0r[a] = w0[a * 64 + lane] * 0.4472135954999579f;
  }
  const int kl2 = (lane & 31) * 2;

  const int nB = (E + 47) / 48;
  for (int b = blockIdx.x; b < nB; b += (int)gridDim.x) {
    const int ebase = b * 48 + wv * 6;
    int outn[6], nsrc[6];
    bool val[6];
    unsigned hp[6];
#pragma unroll
    for (int s = 0; s < 6; ++s) {
      const int e0 = ebase + s;
      val[s] = e0 < E;
      const int e = val[s] ? e0 : 0;
      const int ia = ei[e], ib = ei[E + e];
      if (MODE == 0) { nsrc[s] = ia; outn[s] = ib; }
      else           { nsrc[s] = ib; outn[s] = e;  }
      const float vx = pos[ib * 3]     - pos[ia * 3];
      const float vy = pos[ib * 3 + 1] - pos[ia * 3 + 1];
      const float vz = pos[ib * 3 + 2] - pos[ia * 3 + 2];
      const float rn = rsqrtf(vx * vx + vy * vy + vz * vz);
      const float rx = vx * rn, ry = vy * rn, rz = vz * rn;
      float h;
      if (MODE == 0) {
        float acc = 0.f;
#pragma unroll
        for (int a = 0; a < 5; ++a) acc = fmaf(eattr[(size_t)e * 5 + a], w0r[a], acc);
        h = silu_n(acc);
      } else {
        h = hSrc[(size_t)e * 64 + lane];
      }
      hp[s] = packh2(__shfl(h, kl2), __shfl(h, kl2 + 1));
      if (lane < 16) {
        sF[wv][s][lane] = node[(size_t)nsrc[s] * 40 + lane];
      } else if (lane < 24) {
        const int u = lane - 16;
        const float x0 = node[(size_t)nsrc[s] * 40 + 16 + u * 3];
        const float x1 = node[(size_t)nsrc[s] * 40 + 16 + u * 3 + 1];
        const float x2 = node[(size_t)nsrc[s] * 40 + 16 + u * 3 + 2];
        sF[wv][s][16 + u] = x0 * rx + x1 * ry + x2 * rz;
      } else if (lane < 27) {
        sF[wv][s][24 + (lane - 24)] = (lane == 24) ? rx : ((lane == 25) ? ry : rz);
      }
    }

    float wacc[6][9];
#pragma unroll
    for (int s = 0; s < 6; ++s)
#pragma unroll
      for (int t = 0; t < 9; ++t) wacc[s][t] = 0.f;

    uint4 qa0 = sWa[lane], qb0 = sWb[lane];
    unsigned qc0 = sWc[lane];
#pragma unroll 4
    for (int kp = 0; kp < 32; ++kp) {
      const int kn = (kp + 1) & 31;
      const uint4 qa1 = sWa[kn * 64 + lane];
      const uint4 qb1 = sWb[kn * 64 + lane];
      const unsigned qc1 = sWc[kn * 64 + lane];
#pragma unroll
      for (int s = 0; s < 6; ++s) {
        const unsigned hv2 = ubcast_lane(hp[s], kp);
        wacc[s][0] = dot2h(qa0.x, hv2, wacc[s][0]);
        wacc[s][1] = dot2h(qa0.y, hv2, wacc[s][1]);
        wacc[s][2] = dot2h(qa0.z, hv2, wacc[s][2]);
        wacc[s][3] = dot2h(qa0.w, hv2, wacc[s][3]);
        wacc[s][4] = dot2h(qb0.x, hv2, wacc[s][4]);
        wacc[s][5] = dot2h(qb0.y, hv2, wacc[s][5]);
        wacc[s][6] = dot2h(qb0.z, hv2, wacc[s][6]);
        wacc[s][7] = dot2h(qb0.w, hv2, wacc[s][7]);
        wacc[s][8] = dot2h(qc0,   hv2, wacc[s][8]);
      }
      qa0 = qa1; qb0 = qb1; qc0 = qc1;
    }

    const int ub  = lane >> 4;
    const int ub2 = lane >> 3;
#pragma unroll
    for (int s = 0; s < 6; ++s) {
      float cs = 0.f;
#pragma unroll
      for (int t = 0; t < 6; ++t)
        cs = fmaf(PW0s * sF[wv][s][ub + 4 * t], wacc[s][t], cs);
      cs += __shfl_xor(cs, 16);
      cs += __shfl_xor(cs, 32);

      const float rx = sF[wv][s][24], ry = sF[wv][s][25], rz = sF[wv][s][26];
      const float* xp = &node[(size_t)nsrc[s] * 40 + 16 + ub2 * 3];
      const float xv0 = xp[0], xv1 = xp[1], xv2 = xp[2];
      const float sxw = PW1s * (sF[wv][s][ub2] * wacc[s][6] + sF[wv][s][ub2 + 8] * wacc[s][7]);
      float cv0 = fmaf(PW0s * xv0, wacc[s][8], sxw * rx);
      float cv1 = fmaf(PW0s * xv1, wacc[s][8], sxw * ry);
      float cv2 = fmaf(PW0s * xv2, wacc[s][8], sxw * rz);
      cv0 += __shfl_xor(cv0, 8); cv0 += __shfl_xor(cv0, 16); cv0 += __shfl_xor(cv0, 32);
      cv1 += __shfl_xor(cv1, 8); cv1 += __shfl_xor(cv1, 16); cv1 += __shfl_xor(cv1, 32);
      cv2 += __shfl_xor(cv2, 8); cv2 += __shfl_xor(cv2, 16); cv2 += __shfl_xor(cv2, 32);

      if (val[s]) {
        const size_t ob = (size_t)outn[s] * 40;
        if (lane < 16) out[ob + lane] = cs;
        if (lane < 8) {
          out[ob + 16 + lane * 3]     = cv0;
          out[ob + 16 + lane * 3 + 1] = cv1;
          out[ob + 16 + lane * 3 + 2] = cv2;
        }
      }
    }
  }
}

// ---------------- pack hR into MFMA A-fragments (fp16) ----------------
__global__ __launch_bounds__(512)
void pack_h_kernel(const float* __restrict__ h, uint4* __restrict__ hPf, int nT) {
  const int gid = blockIdx.x * 512 + threadIdx.x;
  if (gid >= nT * 128) return;
  const int l = gid & 63;
  const int H = (gid >> 6) & 1;
  const int T = gid >> 7;
  const int e = T * 16 + (l & 15);
  const int kb = H * 32 + (l >> 4) * 8;
  const float* src = &h[(size_t)e * 64 + kb];
  uint4 q;
  q.x = packh2(src[0], src[1]);
  q.y = packh2(src[2], src[3]);
  q.z = packh2(src[4], src[5]);
  q.w = packh2(src[6], src[7]);
  hPf[gid] = q;
}

// ---------------- precompute vector-path dot table (fp16, parity-separated) --------
__global__ __launch_bounds__(256)
void pack_d_kernel(const float* __restrict__ ligE, const float* __restrict__ node,
                   const int* __restrict__ iei, unsigned short* __restrict__ Dt, int EI) {
  const int gid = blockIdx.x * 256 + threadIdx.x;
  if (gid >= EI * 64) return;
  const int e = gid >> 6, rem = gid & 63;
  const int b = rem >> 5, u = (rem >> 2) & 7, vi = rem & 3;
  const int v = 2 * vi + b;
  const int rec = iei[e];
  const float* xp = &ligE[(size_t)e * 40 + 16 + u * 3];
  const float* yp = &node[(size_t)rec * 40 + 16 + v * 3];
  const float d = (xp[0] * yp[0] + xp[1] * yp[1] + xp[2] * yp[2]) * INV_SQ3;
  Dt[gid] = f16bits(d);
}

// ---------------- rec: MFMA GEMM (h @ RW1 chunk) + fused TP epilogue ----------------
__global__ __launch_bounds__(512, 2)
void rec_kernel(const float* __restrict__ node, const float* __restrict__ ligE,
                const int* __restrict__ iei, const float* __restrict__ RW1,
                const uint4* __restrict__ hPf, const uint2* __restrict__ Dt2,
                float* __restrict__ out, int nT) {
  __shared__ __align__(16) uint4 sB[4096];
  __shared__ __align__(16) unsigned short sFeat[8][320];
  const int tid = threadIdx.x, lane = tid & 63, wv = tid >> 6;
  const int cg = blockIdx.y;

  for (int j = tid; j < 4096; j += 512) {
    const int t = j >> 7, H = (j >> 6) & 1, l = j & 63;
    const int kb = H * 32 + (l >> 4) * 8;
    const float* src = &RW1[(size_t)kb * 2560 + cg * 512 + t * 16 + (l & 15)];
    uint4 q;
    q.x = packh2(src[0],        src[2560]);
    q.y = packh2(src[2 * 2560], src[3 * 2560]);
    q.z = packh2(src[4 * 2560], src[5 * 2560]);
    q.w = packh2(src[6 * 2560], src[7 * 2560]);
    sB[j] = q;
  }
  __syncthreads();

  unsigned short* fW = sFeat[wv];
  const int er0 = (lane >> 4) * 4;
  const int bpar = (lane >> 3) & 1;
  const int c    = lane & 7;
  const int se = lane >> 2, si = lane & 3;

  for (int T = blockIdx.x * 8 + wv; T < nT; T += (int)gridDim.x * 8) {
    const uint4 a0 = hPf[(T * 2 + 0) * 64 + lane];
    const uint4 a1 = hPf[(T * 2 + 1) * 64 + lane];
    const int eg = T * 16 + se;

    if (cg < 4) {
      const int rn = iei[eg];
      const float4 yv = *(const float4*)&node[(size_t)rn * 40 + si * 4];
      *(unsigned*)&fW[(se * 2 + 0) * 8 + 2 * si] = packh2(yv.x, yv.z);
      *(unsigned*)&fW[(se * 2 + 1) * 8 + 2 * si] = packh2(yv.y, yv.w);
      fW[256 + se * 4 + si] = f16bits(ligE[(size_t)eg * 40 + cg * 4 + si]);
    }

    float o[4] = {0.f, 0.f, 0.f, 0.f};
    uint4 b0 = sB[lane], b1 = sB[64 + lane];

    if (cg < 4) {
      uint2 xsR[4]; uint4 ysR[4];
#pragma unroll
      for (int r = 0; r < 4; ++r) {
        const int er = er0 + r;
        ysR[r] = *(const uint4*)&fW[(er * 2 + bpar) * 8];
        xsR[r] = *(const uint2*)&fW[256 + er * 4];
      }
#pragma unroll
      for (int t = 0; t < 32; ++t) {
        uint4 n0, n1;
        if (t < 31) { n0 = sB[(t + 1) * 128 + lane]; n1 = sB[(t + 1) * 128 + 64 + lane]; }
        f32x4 C = {0.f, 0.f, 0.f, 0.f};
        C = mfma16(a0, b0, C);
        C = mfma16(a1, b1, C);
        const int up = t >> 3, vi = t & 7;
#pragma unroll
        for (int r = 0; r < 4; ++r) {
          const float xs = hsel(u2sel(xsR[r], up >> 1), up & 1);
          const float ys = hsel(u4sel(ysR[r], vi >> 1), vi & 1);
          o[r] = fmaf(xs * ys, C[r], o[r]);
        }
        if (t < 31) { b0 = n0; b1 = n1; }
      }
    } else {
#pragma unroll
      for (int pass = 0; pass < 2; ++pass) {
        uint2 dR[4][4];
#pragma unroll
        for (int r = 0; r < 4; ++r) {
          const int e = T * 16 + er0 + r;
#pragma unroll
          for (int uu = 0; uu < 4; ++uu)
            dR[r][uu] = Dt2[(size_t)e * 16 + bpar * 8 + pass * 4 + uu];
        }
#pragma unroll
        for (int tt = 0; tt < 16; ++tt) {
          const int t = pass * 16 + tt;
          uint4 n0, n1;
          if (t < 31) { n0 = sB[(t + 1) * 128 + lane]; n1 = sB[(t + 1) * 128 + 64 + lane]; }
          f32x4 C = {0.f, 0.f, 0.f, 0.f};
          C = mfma16(a0, b0, C);
          C = mfma16(a1, b1, C);
          const int uu = tt >> 2, vi = tt & 3;
#pragma unroll
          for (int r = 0; r < 4; ++r) {
            const float f = hsel(u2sel(dR[r][uu], vi >> 1), vi & 1);
            o[r] = fmaf(f, C[r], o[r]);
          }
          if (t < 31) { b0 = n0; b1 = n1; }
        }
      }
    }

#pragma unroll
    for (int r = 0; r < 4; ++r) {
      const float v = o[r] + __shfl_xor(o[r], 8);
      if ((lane & 8) == 0)
        atomicAdd(&out[(size_t)(T * 16 + er0 + r) * 8 + c], v * PWRECs);
    }
  }
}

extern "C" void kernel_launch(void* const* d_in, const int* in_sizes, int n_in,
                              void* d_out, int out_size, void* d_ws, size_t ws_size,
                              hipStream_t stream) {
  (void)n_in; (void)ws_size;
  const float* x      = (const float*)d_in[0];
  const float* pos    = (const float*)d_in[1];
  const int*   ei     = (const int*)  d_in[2];
  const float* eattr  = (const float*)d_in[3];
  const int*   iei    = (const int*)  d_in[4];
  const float* emb_w0 = (const float*)d_in[5];
  const float* emb_w1 = (const float*)d_in[6];
  const float* imp0   = (const float*)d_in[7];
  const float* m0w0   = (const float*)d_in[8];
  const float* m0w1   = (const float*)d_in[9];
  const float* u0w0   = (const float*)d_in[10];
  const float* u0w1   = (const float*)d_in[11];
  const float* imp1   = (const float*)d_in[12];
  const float* m1w0   = (const float*)d_in[13];
  const float* m1w1   = (const float*)d_in[14];
  const float* u1w0   = (const float*)d_in[15];
  const float* u1w1   = (const float*)d_in[16];
  const float* lw0    = (const float*)d_in[17];
  const float* lw1    = (const float*)d_in[18];
  const float* rw0    = (const float*)d_in[19];
  const float* rw1    = (const float*)d_in[20];

  const int N  = in_sizes[1] / 3;
  const int E  = in_sizes[2] / 2;
  const int EI = in_sizes[4] / 2;

  // ---- persistent layout (28.5 MB proven) ----
  float* node = (float*)d_ws;                        // N*40
  float* regA = node + (size_t)N * 40;               // large shared region
  float* outp = (float*)d_out;

  // msg-phase overlay in regA: CSR ints + Bp + fp32 mbuf (~20 MB < 26.9 MB avail)
  int*   cnt    = (int*)regA;
  int*   starts = cnt + N;
  int*   cursor = starts + N;
  int*   eperm  = cursor + N;
  float* bbase  = (float*)(eperm + E);
  uint4* Bp     = (uint4*)bbase;                     // 36*128 uint4 = 73728 B
  float* mbuf   = bbase + 36 * 128 * 4;              // E*40 fp32

  // inter-phase overlay (msg data dead by then)
  float* hL   = regA;
  float* hR   = hL + (size_t)EI * 64;
  float* ligE = hR + (size_t)EI * 64;
  uint4*          hPf = (uint4*)hL;
  unsigned short* Dt  = (unsigned short*)hR;

  const float inv_sqrt_deg = 1.0f / sqrtf((float)E / (float)N);
  const int nodeBlocks  = (N + 3) / 4;
  const int interBlocks = (EI + 3) / 4;
  const int nT  = EI / 16;             // 2500 (EI divisible by 16)
  const int nTe = (E + 15) / 16;       // 7500
  const int eBlocks = (E + 255) / 256;

  // ---- CSR build (once; edge_index shared by both msg passes) ----
  hipMemsetAsync(cnt, 0, (size_t)N * sizeof(int), stream);
  hipMemsetAsync(cursor, 0, (size_t)N * sizeof(int), stream);
  hist_kernel<<<eBlocks, 256, 0, stream>>>(ei, cnt, E);
  scan_kernel<<<1, 1024, 0, stream>>>(cnt, starts, N);
  scatter_kernel<<<eBlocks, 256, 0, stream>>>(ei, starts, cursor, eperm, E);

  emb_kernel<<<nodeBlocks, 256, 0, stream>>>(x, emb_w0, emb_w1, node, N);

  // message pass 0
  pack_b_kernel<<<18, 256, 0, stream>>>(m0w1, Bp);
  msg_mfma_kernel<<<512, 256, 0, stream>>>(node, pos, ei, eattr, m0w0, Bp, mbuf, E, nTe);
  upd_kernel<<<nodeBlocks, 256, 0, stream>>>(node, mbuf, starts, cnt, eperm,
                                             u0w0, u0w1, imp0, 1.0f, inv_sqrt_deg, N);

  // message pass 1
  pack_b_kernel<<<18, 256, 0, stream>>>(m1w1, Bp);
  msg_mfma_kernel<<<512, 256, 0, stream>>>(node, pos, ei, eattr, m1w0, Bp, mbuf, E, nTe);
  upd_kernel<<<nodeBlocks, 256, 0, stream>>>(node, mbuf, starts, cnt, eperm,
                                             u1w0, u1w1, imp1, 0.5f, inv_sqrt_deg, N);

  // inter edges
  inter_h_kernel<<<interBlocks, 256, 0, stream>>>(pos, iei, lw0, rw0, hL, hR, EI);
  tp_kernel<1><<<512, 512, 0, stream>>>(node, pos, iei, nullptr, nullptr, lw1, hL, ligE, EI);

  // pack A-fragments (reads hR, writes over hL) and D-table (writes over hR)
  pack_h_kernel<<<(nT * 128 + 511) / 512, 512, 0, stream>>>(hR, hPf, nT);
  pack_d_kernel<<<(EI * 64 + 255) / 256, 256, 0, stream>>>(ligE, node, iei, Dt, EI);

  hipMemsetAsync(outp, 0, (size_t)out_size * sizeof(float), stream);
  rec_kernel<<<dim3(102, 5), 512, 0, stream>>>(node, ligE, iei, rw1, hPf, (const uint2*)Dt,
                                               outp, nT);
}